// Round 1
// baseline (1017.697 us; speedup 1.0000x reference)
//
#include <hip/hip_runtime.h>
#include <math.h>

// Problem constants (from reference): N=200 LSTMs, B=100, T=256, D=5, H=20
constexpr int NL = 200;
constexpr int B  = 100;
constexpr int T  = 256;
constexpr int D  = 5;
constexpr int H  = 20;
constexpr int G  = 4 * H;   // 80 gate columns (Keras order: i, f, g, o)

__device__ __forceinline__ float fast_sigmoid(float x) {
    return 1.0f / (1.0f + __expf(-x));
}
__device__ __forceinline__ float fast_tanh(float x) {
    // tanh(x) = 1 - 2/(exp(2x)+1); saturates correctly for |x| large
    return 1.0f - 2.0f / (__expf(2.0f * x) + 1.0f);
}

__global__ __launch_bounds__(256) void init_out_kernel(const float* __restrict__ dense_b,
                                                       float* __restrict__ out, int n) {
    int i = blockIdx.x * 256 + threadIdx.x;
    if (i < n) out[i] = dense_b[i % D];
}

// One block per LSTM n. block=512 (8 waves). Threads tid<500: h = tid%20,
// brem = tid/20 in [0,25); each thread owns batches {brem, brem+25, brem+50, brem+75}
// for its h. U/W gate columns for this h live in registers (reused across 4 batches,
// all T steps). h-state double-buffered in LDS. Dense projection fused: per timestep,
// threads tid<500 (one per (b,d)) reduce over h and atomicAdd into out.
__global__ __launch_bounds__(512, 2) void lstm_fused_kernel(
    const float* __restrict__ x,     // [B][T][D]
    const float* __restrict__ Wg,    // [N][D][4H]
    const float* __restrict__ Ug,    // [N][H][4H]
    const float* __restrict__ bg,    // [N][4H]
    const float* __restrict__ dWg,   // [N*H][D]
    float* __restrict__ out)         // [B][T][D], pre-initialized with dense_b
{
    const int n   = blockIdx.x;
    const int tid = threadIdx.x;

    __shared__ __align__(16) float hbuf[2][B][H];  // 16000 B, double-buffered h state
    __shared__ __align__(16) float xs[B][D];       // current timestep inputs
    __shared__ __align__(16) float Us[H][G];       // staging for U[n]
    __shared__ __align__(16) float Ws[D][G];       // staging for W[n]
    __shared__ __align__(16) float bs[G];
    __shared__ __align__(16) float dWs[H][D];      // dense_W rows n*H..n*H+19

    // Stage this LSTM's weights into LDS (coalesced), then lift into registers.
    for (int i = tid; i < H * G; i += 512) (&Us[0][0])[i] = Ug[n * H * G + i];
    for (int i = tid; i < D * G; i += 512) (&Ws[0][0])[i] = Wg[n * D * G + i];
    for (int i = tid; i < G;     i += 512) bs[i]          = bg[n * G + i];
    for (int i = tid; i < H * D; i += 512) (&dWs[0][0])[i] = dWg[n * H * D + i];
    for (int i = tid; i < B * H; i += 512) (&hbuf[0][0][0])[i] = 0.0f;  // h0 = 0
    __syncthreads();

    const bool comp = (tid < 500);
    const int h    = tid % H;     // 0..19
    const int brem = tid / H;     // 0..24 when comp

    float Ur[H][4];   // U[n][k][g*H+h] — 80 VGPRs, reused every step
    float Wr[D][4];   // W[n][d][g*H+h] — 20 VGPRs
    float br[4];
    if (comp) {
        #pragma unroll
        for (int g = 0; g < 4; ++g) {
            br[g] = bs[g * H + h];
            #pragma unroll
            for (int k = 0; k < H; ++k) Ur[k][g] = Us[k][g * H + h];
            #pragma unroll
            for (int d = 0; d < D; ++d) Wr[d][g] = Ws[d][g * H + h];
        }
    }
    float c[4] = {0.0f, 0.0f, 0.0f, 0.0f};  // cell state, one per owned batch

    const int db = tid / D;   // 0..99 when tid < 500 (dense/x-staging role)
    const int dd = tid % D;   // 0..4

    int cur = 0;
    for (int t = 0; t < T; ++t) {
        // Stage x_t (500 floats) into LDS
        if (tid < B * D) xs[db][dd] = x[(db * T + t) * D + dd];
        __syncthreads();

        if (comp) {
            #pragma unroll
            for (int j = 0; j < 4; ++j) {
                const int b = brem + 25 * j;
                float z0 = br[0], z1 = br[1], z2 = br[2], z3 = br[3];
                #pragma unroll
                for (int d = 0; d < D; ++d) {
                    const float xv = xs[b][d];
                    z0 = fmaf(xv, Wr[d][0], z0);
                    z1 = fmaf(xv, Wr[d][1], z1);
                    z2 = fmaf(xv, Wr[d][2], z2);
                    z3 = fmaf(xv, Wr[d][3], z3);
                }
                #pragma unroll
                for (int k = 0; k < H; ++k) {
                    const float hv = hbuf[cur][b][k];   // b128-vectorizable, broadcast-friendly
                    z0 = fmaf(hv, Ur[k][0], z0);
                    z1 = fmaf(hv, Ur[k][1], z1);
                    z2 = fmaf(hv, Ur[k][2], z2);
                    z3 = fmaf(hv, Ur[k][3], z3);
                }
                const float ig = fast_sigmoid(z0);
                const float fg = fast_sigmoid(z1);
                const float gg = fast_tanh(z2);
                const float og = fast_sigmoid(z3);
                const float cn = fmaf(fg, c[j], ig * gg);
                c[j] = cn;
                hbuf[cur ^ 1][b][h] = og * fast_tanh(cn);
            }
        }
        __syncthreads();

        // Fused dense: partial[b][d] = sum_h hnew[b][h] * dW[n*H+h][d], atomically
        // accumulated into out (init'd with dense_b by init_out_kernel).
        if (tid < B * D) {
            float acc = 0.0f;
            #pragma unroll
            for (int k = 0; k < H; ++k)
                acc = fmaf(hbuf[cur ^ 1][db][k], dWs[k][dd], acc);
            atomicAdd(&out[(db * T + t) * D + dd], acc);
        }
        cur ^= 1;
    }
}

extern "C" void kernel_launch(void* const* d_in, const int* in_sizes, int n_in,
                              void* d_out, int out_size, void* d_ws, size_t ws_size,
                              hipStream_t stream) {
    const float* x   = (const float*)d_in[0];  // [B,T,D]
    const float* Wg  = (const float*)d_in[1];  // [N,D,4H]
    const float* Ug  = (const float*)d_in[2];  // [N,H,4H]
    const float* bg  = (const float*)d_in[3];  // [N,4H]
    const float* dWg = (const float*)d_in[4];  // [N*H,D]
    const float* dbv = (const float*)d_in[5];  // [D]
    float* out = (float*)d_out;

    // out = dense_b broadcast; lstm kernel atomically accumulates partials
    init_out_kernel<<<(out_size + 255) / 256, 256, 0, stream>>>(dbv, out, out_size);
    lstm_fused_kernel<<<NL, 512, 0, stream>>>(x, Wg, Ug, bg, dWg, out);
}

// Round 2
// 667.438 us; speedup vs baseline: 1.5248x; 1.5248x over previous
//
#include <hip/hip_runtime.h>
#include <math.h>

// Problem constants: N=200 LSTMs, B=100, T=256, D=5 (io), H=20 (units)
constexpr int NL = 200;
constexpr int B  = 100;
constexpr int T  = 256;
constexpr int D  = 5;
constexpr int H  = 20;
constexpr int G  = 4 * H;       // 80 gate columns (Keras order: i, f, g, o)
constexpr int CH  = 5;          // batch chunks per LSTM
constexpr int BC  = B / CH;     // 20 batches per block
constexpr int CT  = BC * H;     // 400 compute threads
constexpr int DT  = BC * D;     // 100 dense threads
constexpr int BLK = 448;        // 7 waves (>= CT)

__device__ __forceinline__ float fast_sigmoid(float x) {
    return 1.0f / (1.0f + __expf(-x));
}
__device__ __forceinline__ float fast_tanh(float x) {
    return 1.0f - 2.0f / (__expf(2.0f * x) + 1.0f);
}

__global__ __launch_bounds__(256) void init_out_kernel(const float* __restrict__ dense_b,
                                                       float* __restrict__ out, int n) {
    int i = blockIdx.x * 256 + threadIdx.x;
    if (i < n) out[i] = dense_b[i % D];
}

// One block per (lstm n, batch-chunk). Thread owns one (h, b): U columns for its
// h in registers (80 VGPR), W/bias/dense_W staged in LDS, h-state double-buffered
// in LDS. x read straight from L2 with a t+1 prefetch. ONE barrier per timestep.
// Dense projection partials go to private workspace (no atomics) when USE_WS.
template<bool USE_WS>
__global__ __launch_bounds__(BLK, 4) void lstm_kernel(
    const float* __restrict__ x,     // [B][T][D]
    const float* __restrict__ Wg,    // [N][D][4H]
    const float* __restrict__ Ug,    // [N][H][4H]
    const float* __restrict__ bg,    // [N][4H]
    const float* __restrict__ dWg,   // [N*H][D]
    float* __restrict__ pw,          // [N*CH][T][DT] partials (USE_WS)
    float* __restrict__ out)         // [B][T][D] (atomic fallback)
{
    const int blk   = blockIdx.x;
    const int n     = blk / CH;
    const int chunk = blk % CH;
    const int b0    = chunk * BC;
    const int tid   = threadIdx.x;

    __shared__ __align__(16) float hbuf[2][BC][H];   // 3.2 KB, double-buffered h
    __shared__ __align__(16) float Us[H][G];         // 6.4 KB staging for U[n]
    __shared__ __align__(16) float Ws[D][G];         // 1.6 KB
    __shared__ __align__(16) float bs[G];
    __shared__ __align__(16) float dWs[H][D];

    for (int i = tid; i < H * G; i += BLK) (&Us[0][0])[i]  = Ug[n * H * G + i];
    for (int i = tid; i < D * G; i += BLK) (&Ws[0][0])[i]  = Wg[n * D * G + i];
    for (int i = tid; i < G;     i += BLK) bs[i]           = bg[n * G + i];
    for (int i = tid; i < H * D; i += BLK) (&dWs[0][0])[i] = dWg[n * H * D + i];
    for (int i = tid; i < 2 * BC * H; i += BLK) (&hbuf[0][0][0])[i] = 0.0f;
    __syncthreads();

    // clamp extra threads (tid 400..447) to duplicates of the last work item;
    // their LDS writes duplicate identical values (benign).
    const int ct  = tid < CT ? tid : CT - 1;
    const int h   = ct % H;
    const int blb = ct / H;              // local batch 0..19
    const int b   = b0 + blb;            // global batch

    float4 Ur[H];                        // U[n][k][{i,f,g,o}*H + h] — 80 VGPRs
    #pragma unroll
    for (int k = 0; k < H; ++k)
        Ur[k] = make_float4(Us[k][h], Us[k][H + h], Us[k][2 * H + h], Us[k][3 * H + h]);
    const float4 br = make_float4(bs[h], bs[H + h], bs[2 * H + h], bs[3 * H + h]);

    const float* xp = x + (size_t)b * T * D;
    float xr[D], xn[D];
    #pragma unroll
    for (int d = 0; d < D; ++d) xr[d] = xp[d];   // t = 0

    float c = 0.0f;
    int cur = 0;

    for (int t = 0; t < T; ++t) {
        float z0 = br.x, z1 = br.y, z2 = br.z, z3 = br.w;
        #pragma unroll
        for (int d = 0; d < D; ++d) {
            const float xv = xr[d];
            z0 = fmaf(xv, Ws[d][h],         z0);
            z1 = fmaf(xv, Ws[d][H + h],     z1);
            z2 = fmaf(xv, Ws[d][2 * H + h], z2);
            z3 = fmaf(xv, Ws[d][3 * H + h], z3);
        }
        const float4* hrow = (const float4*)&hbuf[cur][blb][0];
        #pragma unroll
        for (int kk = 0; kk < H / 4; ++kk) {
            const float4 hv = hrow[kk];
            z0 = fmaf(hv.x, Ur[kk*4+0].x, z0); z1 = fmaf(hv.x, Ur[kk*4+0].y, z1);
            z2 = fmaf(hv.x, Ur[kk*4+0].z, z2); z3 = fmaf(hv.x, Ur[kk*4+0].w, z3);
            z0 = fmaf(hv.y, Ur[kk*4+1].x, z0); z1 = fmaf(hv.y, Ur[kk*4+1].y, z1);
            z2 = fmaf(hv.y, Ur[kk*4+1].z, z2); z3 = fmaf(hv.y, Ur[kk*4+1].w, z3);
            z0 = fmaf(hv.z, Ur[kk*4+2].x, z0); z1 = fmaf(hv.z, Ur[kk*4+2].y, z1);
            z2 = fmaf(hv.z, Ur[kk*4+2].z, z2); z3 = fmaf(hv.z, Ur[kk*4+2].w, z3);
            z0 = fmaf(hv.w, Ur[kk*4+3].x, z0); z1 = fmaf(hv.w, Ur[kk*4+3].y, z1);
            z2 = fmaf(hv.w, Ur[kk*4+3].z, z2); z3 = fmaf(hv.w, Ur[kk*4+3].w, z3);
        }
        // prefetch x for t+1 (clamped; latency hides under gate math + barrier)
        const int tn = (t + 1 < T) ? t + 1 : T - 1;
        #pragma unroll
        for (int d = 0; d < D; ++d) xn[d] = xp[tn * D + d];

        const float ig = fast_sigmoid(z0);
        const float fg = fast_sigmoid(z1);
        const float gg = fast_tanh(z2);
        const float og = fast_sigmoid(z3);
        c = fmaf(fg, c, ig * gg);
        hbuf[cur ^ 1][blb][h] = og * fast_tanh(c);
        __syncthreads();   // h(t) visible to dense + next step's z

        if (tid < DT) {
            const int bb = tid / D, dd = tid % D;
            float acc = 0.0f;
            const float4* hr = (const float4*)&hbuf[cur ^ 1][bb][0];
            #pragma unroll
            for (int kk = 0; kk < H / 4; ++kk) {
                const float4 hv = hr[kk];
                acc = fmaf(hv.x, dWs[kk*4+0][dd], acc);
                acc = fmaf(hv.y, dWs[kk*4+1][dd], acc);
                acc = fmaf(hv.z, dWs[kk*4+2][dd], acc);
                acc = fmaf(hv.w, dWs[kk*4+3][dd], acc);
            }
            if (USE_WS) {
                pw[((size_t)blk * T + t) * DT + tid] = acc;   // private, contiguous
            } else {
                atomicAdd(&out[((size_t)(b0 + bb) * T + t) * D + dd], acc);
            }
        }
        #pragma unroll
        for (int d = 0; d < D; ++d) xr[d] = xn[d];
        cur ^= 1;
    }
}

// out[b][t][d] = dense_b[d] + sum over 200 lstms of pw[(n*CH + b/BC)][t][(b%BC)*D+d]
__global__ __launch_bounds__(512) void reduce_kernel(
    const float* __restrict__ pw, const float* __restrict__ dense_b,
    float* __restrict__ out)
{
    const int t    = blockIdx.x;
    const int flat = threadIdx.x;          // (b,d) flattened, 0..499
    if (flat >= B * D) return;
    const int bb    = flat / D;
    const int dd    = flat % D;
    const int chunk = bb / BC;
    const int idx   = (bb % BC) * D + dd;  // 0..99, consecutive across lanes

    float acc = dense_b[dd];
    const float* p = pw + ((size_t)chunk * T + t) * DT + idx;
    constexpr size_t stride = (size_t)CH * T * DT;   // next n, same chunk/t
    #pragma unroll 10
    for (int n = 0; n < NL; ++n) acc += p[n * stride];
    out[((size_t)bb * T + t) * D + dd] = acc;
}

extern "C" void kernel_launch(void* const* d_in, const int* in_sizes, int n_in,
                              void* d_out, int out_size, void* d_ws, size_t ws_size,
                              hipStream_t stream) {
    const float* x   = (const float*)d_in[0];
    const float* Wg  = (const float*)d_in[1];
    const float* Ug  = (const float*)d_in[2];
    const float* bg  = (const float*)d_in[3];
    const float* dWg = (const float*)d_in[4];
    const float* dbv = (const float*)d_in[5];
    float* out = (float*)d_out;

    const size_t need = (size_t)NL * CH * T * DT * sizeof(float);   // 102.4 MB
    if (ws_size >= need) {
        float* pw = (float*)d_ws;
        lstm_kernel<true><<<NL * CH, BLK, 0, stream>>>(x, Wg, Ug, bg, dWg, pw, out);
        reduce_kernel<<<T, 512, 0, stream>>>(pw, dbv, out);
    } else {
        init_out_kernel<<<(out_size + 255) / 256, 256, 0, stream>>>(dbv, out, out_size);
        lstm_kernel<false><<<NL * CH, BLK, 0, stream>>>(x, Wg, Ug, bg, dWg, nullptr, out);
    }
}

// Round 3
// 432.846 us; speedup vs baseline: 2.3512x; 1.5420x over previous
//
#include <hip/hip_runtime.h>
#include <math.h>

// Problem constants: N=200 LSTMs, B=100, T=256, D=5 (io), H=20 (units)
constexpr int NL = 200;
constexpr int B  = 100;
constexpr int T  = 256;
constexpr int D  = 5;
constexpr int H  = 20;
constexpr int NG  = NL * B;                     // 20000 (lstm, batch) groups
constexpr int GPW = 3;                          // groups per wave (3*20=60 of 64 lanes)
constexpr int WPB = 4;                          // independent waves per block
constexpr int NWAVES = (NG + GPW - 1) / GPW;    // 6667
constexpr int NBLKS  = (NWAVES + WPB - 1) / WPB;// 1667

__device__ __forceinline__ float rcpf(float x) { return __builtin_amdgcn_rcpf(x); }
__device__ __forceinline__ float sigm(float x) { return rcpf(1.0f + __expf(-x)); }
__device__ __forceinline__ float tanh_fast(float x) {
    return fmaf(-2.0f, rcpf(__expf(2.0f * x) + 1.0f), 1.0f);
}

__global__ __launch_bounds__(256) void init_out_kernel(const float* __restrict__ dense_b,
                                                       float* __restrict__ out, int n) {
    int i = blockIdx.x * 256 + threadIdx.x;
    if (i < n) out[i] = dense_b[i % D];
}

// Wave-synchronous LSTM: each wave owns 3 (lstm n, batch b) groups of 20 lanes
// (lane = h). U/W/bias columns live in REGISTERS (loaded from global so the
// compiler cannot rematerialize them; asm-pinned). h-state exchanged through a
// tiny wave-private LDS double buffer — same-wave DS ops are processed in
// order, so NO barriers exist in the timestep loop. Dense projection fused:
// lanes 0..59 = 15 (b,d) items x 4 k-quarters, combined with 2 shfl_xor.
template<bool USE_WS>
__global__ __launch_bounds__(64 * WPB, 3) void lstm_wave_kernel(
    const float* __restrict__ x,    // [B][T][D]
    const float* __restrict__ Wg,   // [N][D][4H]
    const float* __restrict__ Ug,   // [N][H][4H]
    const float* __restrict__ bg,   // [N][4H]
    const float* __restrict__ dWg,  // [N*H][D]
    float* __restrict__ pw,         // [N][T][B*D] partials (USE_WS)
    float* __restrict__ out)        // [B][T][D] (atomic fallback)
{
    const int tid  = threadIdx.x;
    const int wl   = tid >> 6;                   // wave within block
    const int lane = tid & 63;
    const long wav = (long)blockIdx.x * WPB + wl;

    const int grp = lane / 20;                   // 0..3 (grp 3 = 4 spare lanes)
    const bool gl = grp < 3;                     // gate lane?
    const int cg  = gl ? grp : 0;                // clamped group
    const int h   = lane % 20;

    long gid = wav * GPW + cg; if (gid > NG - 1) gid = NG - 1;
    const int n = (int)(gid / B), b = (int)(gid % B);

    // ---- dense role (lanes 0..59): item = (b',d'), kq = k-quarter ----
    const int item = lane >> 2;                  // 0..15
    const int kq   = lane & 3;
    const int it5  = (item < 15) ? item / 5 : 0;
    const int dd   = (item < 15) ? item % 5 : 0;
    long dgid = wav * GPW + it5; if (dgid > NG - 1) dgid = NG - 1;
    const int dn = (int)(dgid / B), db = (int)(dgid % B);
    float dwr[5];
    #pragma unroll
    for (int j = 0; j < 5; ++j) dwr[j] = dWg[(dn * H + kq * 5 + j) * D + dd];

    // ---- per-lane weight columns in registers (from GLOBAL; asm-pinned) ----
    const float* up = Ug + (size_t)n * H * 4 * H + h;
    const float* wp = Wg + (size_t)n * D * 4 * H + h;
    const float* bp = bg + (size_t)n * 4 * H + h;
    float Ur[H][4], Wr[D][4], br[4];
    #pragma unroll
    for (int g = 0; g < 4; ++g) {
        br[g] = bp[g * H];
        #pragma unroll
        for (int k = 0; k < H; ++k) Ur[k][g] = up[k * 4 * H + g * H];
        #pragma unroll
        for (int d = 0; d < D; ++d) Wr[d][g] = wp[d * 4 * H + g * H];
    }
    #pragma unroll
    for (int k = 0; k < H; ++k)
        asm volatile("" : "+v"(Ur[k][0]), "+v"(Ur[k][1]), "+v"(Ur[k][2]), "+v"(Ur[k][3]));

    // wave-private h double buffer (no cross-wave sharing -> no barriers)
    __shared__ __align__(16) float hbuf[WPB][2][GPW][H];
    if (lane < GPW * H) (&hbuf[wl][0][0][0])[lane] = 0.0f;   // h0 = 0
    __builtin_amdgcn_wave_barrier();

    const float* xq = x + (size_t)b * T * D;
    float* pwp = USE_WS ? (pw + ((size_t)dn * T) * (B * D) + db * D + dd)
                        : (out + (size_t)db * T * D + dd);

    float c = 0.0f;
    int cur = 0;
    #pragma unroll 2
    for (int t = 0; t < T; ++t) {
        float xr[D];
        #pragma unroll
        for (int d = 0; d < D; ++d) xr[d] = xq[d];

        float z0 = br[0], z1 = br[1], z2 = br[2], z3 = br[3];
        const float4* hr = (const float4*)&hbuf[wl][cur][cg][0];
        #pragma unroll
        for (int kk = 0; kk < H / 4; ++kk) {
            const float4 hv = hr[kk];
            z0 = fmaf(hv.x, Ur[4*kk+0][0], z0); z1 = fmaf(hv.x, Ur[4*kk+0][1], z1);
            z2 = fmaf(hv.x, Ur[4*kk+0][2], z2); z3 = fmaf(hv.x, Ur[4*kk+0][3], z3);
            z0 = fmaf(hv.y, Ur[4*kk+1][0], z0); z1 = fmaf(hv.y, Ur[4*kk+1][1], z1);
            z2 = fmaf(hv.y, Ur[4*kk+1][2], z2); z3 = fmaf(hv.y, Ur[4*kk+1][3], z3);
            z0 = fmaf(hv.z, Ur[4*kk+2][0], z0); z1 = fmaf(hv.z, Ur[4*kk+2][1], z1);
            z2 = fmaf(hv.z, Ur[4*kk+2][2], z2); z3 = fmaf(hv.z, Ur[4*kk+2][3], z3);
            z0 = fmaf(hv.w, Ur[4*kk+3][0], z0); z1 = fmaf(hv.w, Ur[4*kk+3][1], z1);
            z2 = fmaf(hv.w, Ur[4*kk+3][2], z2); z3 = fmaf(hv.w, Ur[4*kk+3][3], z3);
        }
        #pragma unroll
        for (int d = 0; d < D; ++d) {
            const float xv = xr[d];
            z0 = fmaf(xv, Wr[d][0], z0); z1 = fmaf(xv, Wr[d][1], z1);
            z2 = fmaf(xv, Wr[d][2], z2); z3 = fmaf(xv, Wr[d][3], z3);
        }

        const float ig = sigm(z0);
        const float fg = sigm(z1);
        const float gg = tanh_fast(z2);
        const float og = sigm(z3);
        c = fmaf(fg, c, ig * gg);
        const float hv = og * tanh_fast(c);

        if (gl) hbuf[wl][cur ^ 1][grp][h] = hv;
        __builtin_amdgcn_wave_barrier();   // same-wave DS ops are in-order; fence the compiler

        if (lane < 60) {
            const float* hd = &hbuf[wl][cur ^ 1][it5][kq * 5];
            float acc = hd[0] * dwr[0];
            #pragma unroll
            for (int j = 1; j < 5; ++j) acc = fmaf(hd[j], dwr[j], acc);
            acc += __shfl_xor(acc, 1);
            acc += __shfl_xor(acc, 2);
            if (kq == 0) {
                if (USE_WS) *pwp = acc;                 // private slot, coalesced-ish
                else        atomicAdd(pwp, acc);        // fallback
            }
        }
        xq  += D;
        pwp += USE_WS ? (B * D) : D;
        cur ^= 1;
    }
}

// out[b][t][d] = dense_b[d] + sum_n pw[n][t][b*D+d]  (fully coalesced reads)
__global__ __launch_bounds__(512) void reduce_kernel(
    const float* __restrict__ pw, const float* __restrict__ dense_b,
    float* __restrict__ out)
{
    const int t    = blockIdx.x;
    const int flat = threadIdx.x;              // (b,d) flattened, 0..499
    if (flat >= B * D) return;
    float acc = dense_b[flat % D];
    const float* p = pw + (size_t)t * (B * D) + flat;
    constexpr size_t stride = (size_t)T * B * D;
    #pragma unroll 8
    for (int n = 0; n < NL; ++n) acc += p[n * stride];
    out[((size_t)(flat / D) * T + t) * D + flat % D] = acc;
}

extern "C" void kernel_launch(void* const* d_in, const int* in_sizes, int n_in,
                              void* d_out, int out_size, void* d_ws, size_t ws_size,
                              hipStream_t stream) {
    const float* x   = (const float*)d_in[0];
    const float* Wg  = (const float*)d_in[1];
    const float* Ug  = (const float*)d_in[2];
    const float* bg  = (const float*)d_in[3];
    const float* dWg = (const float*)d_in[4];
    const float* dbv = (const float*)d_in[5];
    float* out = (float*)d_out;

    const size_t need = (size_t)NL * T * B * D * sizeof(float);   // 102.4 MB
    if (ws_size >= need) {
        float* pw = (float*)d_ws;
        lstm_wave_kernel<true><<<NBLKS, 64 * WPB, 0, stream>>>(x, Wg, Ug, bg, dWg, pw, out);
        reduce_kernel<<<T, 512, 0, stream>>>(pw, dbv, out);
    } else {
        init_out_kernel<<<(out_size + 255) / 256, 256, 0, stream>>>(dbv, out, out_size);
        lstm_wave_kernel<false><<<NBLKS, 64 * WPB, 0, stream>>>(x, Wg, Ug, bg, dWg, nullptr, out);
    }
}